// Round 6
// baseline (599.417 us; speedup 1.0000x reference)
//
#include <hip/hip_runtime.h>
#include <cstdint>
#include <cstddef>

#define EPS_V 1e-5f
#define SLOTS 16

typedef __attribute__((ext_vector_type(8))) short bf16x8;
typedef __attribute__((ext_vector_type(4))) float f32x4;

__device__ __forceinline__ unsigned short f2b(float f) {
    unsigned u = __float_as_uint(f);
    u = (u + 0x7FFFu + ((u >> 16) & 1u)) >> 16;      // RNE
    return (unsigned short)u;
}

__device__ __forceinline__ bf16x8 cvt8(float4 a, float4 b) {
    bf16x8 r;
    r[0] = (short)f2b(a.x); r[1] = (short)f2b(a.y);
    r[2] = (short)f2b(a.z); r[3] = (short)f2b(a.w);
    r[4] = (short)f2b(b.x); r[5] = (short)f2b(b.y);
    r[6] = (short)f2b(b.z); r[7] = (short)f2b(b.w);
    return r;
}

__device__ __forceinline__ float b2f(unsigned short u) {
    return __uint_as_float((unsigned)u << 16);
}

__device__ __forceinline__ void b2f8(bf16x8 v, float4& a, float4& b) {
    a.x = b2f((unsigned short)v[0]); a.y = b2f((unsigned short)v[1]);
    a.z = b2f((unsigned short)v[2]); a.w = b2f((unsigned short)v[3]);
    b.x = b2f((unsigned short)v[4]); b.y = b2f((unsigned short)v[5]);
    b.z = b2f((unsigned short)v[6]); b.w = b2f((unsigned short)v[7]);
}

__device__ __forceinline__ float4 nrm4(float4 v, const float* ss, const float* tt, int c) {
    v.x = fmaf(v.x, ss[c + 0], tt[c + 0]);
    v.y = fmaf(v.y, ss[c + 1], tt[c + 1]);
    v.z = fmaf(v.z, ss[c + 2], tt[c + 2]);
    v.w = fmaf(v.w, ss[c + 3], tt[c + 3]);
    return v;
}

__device__ __forceinline__ void ntst(float* p, float4 v) {
    f32x4 w; w[0] = v.x; w[1] = v.y; w[2] = v.z; w[3] = v.w;
    __builtin_nontemporal_store(w, (f32x4*)p);
}

// bijective XCD-aware block swizzle (8 XCDs): consecutive logical blocks land
// on the same XCD -> monotone gather ranges stay in one XCD's L2.
__device__ __forceinline__ int xswz(int bid, int nB) {
    int q = nB >> 3, r = nB & 7;
    int x = bid & 7, i = bid >> 3;
    int base = (x < r) ? x * (q + 1) : r * (q + 1) + (x - r) * q;
    return base + i;
}

__device__ __forceinline__ void slot_sum(const float* st, int c, float& s0, float& s1) {
    s0 = 0.f; s1 = 0.f;
    #pragma unroll
    for (int s = 0; s < SLOTS; s++) {
        s0 += st[s * 256 + c];
        s1 += st[s * 256 + 128 + c];
    }
}

template <int C>
__device__ __forceinline__ void mk_norm(const float* st_in, int Min,
                                        const float* gw, const float* bw,
                                        float* ss, float* tt) {
    if (threadIdx.x < C) {
        int c = threadIdx.x;
        float s0, s1; slot_sum(st_in, c, s0, s1);
        float invM = 1.0f / (float)Min;
        float mu = s0 * invM;
        float var = fmaf(s1, invM, -mu * mu);
        float s = rsqrtf(var + EPS_V) * gw[c];
        ss[c] = s; tt[c] = fmaf(-mu, s, bw[c]);
    }
}

// ---------------- fused preprocessing: detect + pack + wshuf + writer-max ---
__device__ __forceinline__ void pack_one(const void* mask, int r, int isByte,
                                         unsigned char* pm) {
    unsigned byte = 0;
    if (isByte) {
        const unsigned char* mb = (const unsigned char*)mask;
        #pragma unroll
        for (int k = 0; k < 8; k++) byte |= (mb[(size_t)r * 8 + k] ? 1u : 0u) << k;
    } else {
        const int* mi = (const int*)mask;
        #pragma unroll
        for (int k = 0; k < 8; k++) byte |= (mi[(size_t)r * 8 + k] ? 1u : 0u) << k;
    }
    pm[r] = (unsigned char)byte;
}

// Wshuf[((t*KB+kb)*NB+nb)*64 + L][j] = bf16( W[t][kb*32 + (L>>4)*8 + j][nb*16 + (L&15)] )
__device__ __forceinline__ void wshuf_one(const float* W, int Cin, int Cout,
                                          unsigned short* dst, int g) {
    int KB = Cin >> 5, NB = Cout >> 4;
    int L = g & 63;
    int rest = g >> 6;
    int nb = rest % NB; rest /= NB;
    int kb = rest % KB; int t = rest / KB;
    int q = L >> 4, col = nb * 16 + (L & 15);
    const float* src = W + ((size_t)t * Cin + kb * 32 + q * 8) * Cout + col;
    unsigned short* d = dst + (size_t)g * 8;
    #pragma unroll
    for (int j = 0; j < 8; j++) d[j] = f2b(src[(size_t)j * Cout]);
}

__global__ __launch_bounds__(256)
void k_prep(const void* msk1, int M1, const void* msk2, int M2,
            unsigned char* __restrict__ pm1, unsigned char* __restrict__ pm2,
            const float* __restrict__ W1, const float* __restrict__ W2,
            const float* __restrict__ W3, const float* __restrict__ W4,
            unsigned short* __restrict__ ws1, unsigned short* __restrict__ ws2,
            unsigned short* __restrict__ ws3, unsigned short* __restrict__ ws4,
            const int* __restrict__ par2, int* __restrict__ wmax2,
            const int* __restrict__ par1, int* __restrict__ wmax1,
            int N0, int do_wmax) {
    __shared__ int sfl;
    int P1 = (M1 + 255) >> 8, P2 = (M2 + 255) >> 8;
    int b = blockIdx.x, tid = threadIdx.x;
    if (b < P1 + P2) {
        // per-block dtype detection on a fixed msk1 window (L2-hot)
        if (tid == 0) sfl = 0;
        __syncthreads();
        const unsigned* wm = (const unsigned*)msk1;
        int nw = M1 * 2; if (nw > 4096) nw = 4096;
        unsigned loc = 0;
        for (int i = tid; i < nw; i += 256) if (wm[i] > 1u) loc = 1u;
        if (loc) atomicOr(&sfl, 1);
        __syncthreads();
        int isB = sfl;
        if (b < P1) { int r = b * 256 + tid; if (r < M1) pack_one(msk1, r, isB, pm1); }
        else { int r = (b - P1) * 256 + tid; if (r < M2) pack_one(msk2, r, isB, pm2); }
        return;
    }
    b -= P1 + P2;
    if (b < 8)  { wshuf_one(W1, 32, 64,  ws1, b * 256 + tid); return; }
    b -= 8;
    if (b < 32) { wshuf_one(W2, 64, 128, ws2, b * 256 + tid); return; }
    b -= 32;
    if (b < 32) { wshuf_one(W3, 128, 64, ws3, b * 256 + tid); return; }
    b -= 32;
    if (b < 8)  { wshuf_one(W4, 64, 32,  ws4, b * 256 + tid); return; }
    b -= 8;
    if (!do_wmax) return;
    if (b < P1) { int r = b * 256 + tid; if (r < M1) atomicMax(&wmax2[par2[r]], r + 1); return; }
    b -= P1;
    { int r = b * 256 + tid; if (r < N0) atomicMax(&wmax1[par1[r]], r + 1); }
}

// ================= fused bf16-intermediate path =============================

// conv1: x f32 -> R1 raw bf16. B-frags from L2, no LDS. XCD-swizzled.
__global__ __launch_bounds__(256, 3)
void k_conv1b(const float* __restrict__ xin, const unsigned short* __restrict__ Wsh,
              const int* __restrict__ idx, const unsigned char* __restrict__ pm,
              unsigned short* __restrict__ rawout, float* __restrict__ st, int M) {
    __shared__ float ls[2 * 64];
    if (threadIdx.x < 128) ls[threadIdx.x] = 0.f;
    __syncthreads();
    const int lane = threadIdx.x & 63, wid = threadIdx.x >> 6;
    const int q = lane >> 4, li = lane & 15;
    int gi = xswz(blockIdx.x, gridDim.x);
    int tile = gi * 4 + wid;
    float sum[4] = {0, 0, 0, 0}, sq[4] = {0, 0, 0, 0};
    if (tile * 16 < M) {
        int rowA = tile * 16 + li;
        unsigned m = pm[rowA];
        const int4* ipv = (const int4*)(idx + (size_t)rowA * 8);
        int4 ia = ipv[0], ib = ipv[1];
        int ipr[8] = {ia.x, ia.y, ia.z, ia.w, ib.x, ib.y, ib.z, ib.w};
        float4 F0[8], F1[8];
        #pragma unroll
        for (int t = 0; t < 8; t++) {
            const float4* p = (const float4*)(xin + (size_t)ipr[t] * 32 + q * 8);
            F0[t] = p[0]; F1[t] = p[1];
        }
        f32x4 acc[4];
        #pragma unroll
        for (int nb = 0; nb < 4; nb++) acc[nb] = (f32x4)0.f;
        bf16x8 z8 = (bf16x8)(short)0;
        #pragma unroll
        for (int t = 0; t < 8; t++) {
            bool valid = (m >> t) & 1u;
            bf16x8 av = valid ? cvt8(F0[t], F1[t]) : z8;
            #pragma unroll
            for (int nb = 0; nb < 4; nb++) {
                bf16x8 bb = *(const bf16x8*)(Wsh + ((size_t)(t * 4 + nb) * 64 + lane) * 8);
                acc[nb] = __builtin_amdgcn_mfma_f32_16x16x32_bf16(av, bb, acc[nb], 0, 0, 0);
            }
        }
        int rowD = tile * 16 + q * 4;
        #pragma unroll
        for (int nb = 0; nb < 4; nb++)
            #pragma unroll
            for (int r = 0; r < 4; r++) {
                float v = acc[nb][r];
                rawout[(size_t)(rowD + r) * 64 + nb * 16 + li] = f2b(v);
                sum[nb] += v; sq[nb] = fmaf(v, v, sq[nb]);
            }
    }
    #pragma unroll
    for (int nb = 0; nb < 4; nb++) {
        int c = nb * 16 + li;
        atomicAdd(&ls[c], sum[nb]); atomicAdd(&ls[64 + c], sq[nb]);
    }
    __syncthreads();
    int slot = (blockIdx.x & (SLOTS - 1)) << 8;
    if (threadIdx.x < 64) {
        atomicAdd(&st[slot + threadIdx.x], ls[threadIdx.x]);
        atomicAdd(&st[slot + 128 + threadIdx.x], ls[64 + threadIdx.x]);
    }
}

// conv2: R1 bf16 -> (normalized x_up1 f32 scatter to sD) + R2 raw bf16.
__global__ __launch_bounds__(256, 3)
void k_conv2b(const unsigned short* __restrict__ rin, const unsigned short* __restrict__ Wsh,
              const int* __restrict__ idx, const unsigned char* __restrict__ pm,
              unsigned short* __restrict__ rawout, float* __restrict__ st, int M,
              const float* __restrict__ st_in, const float* __restrict__ gw,
              const float* __restrict__ bw, int Min, float* __restrict__ nout) {
    __shared__ float ls[2 * 128];
    __shared__ float ss[64], tt[64];
    ls[threadIdx.x] = 0.f;
    mk_norm<64>(st_in, Min, gw, bw, ss, tt);
    __syncthreads();
    const int lane = threadIdx.x & 63, wid = threadIdx.x >> 6;
    const int q = lane >> 4, li = lane & 15;
    int gi = xswz(blockIdx.x, gridDim.x);
    int tile = gi * 4 + wid;
    int rowA = tile * 16 + li;
    unsigned m = pm[rowA];
    const int4* ipv = (const int4*)(idx + (size_t)rowA * 8);
    int4 ia = ipv[0], ib = ipv[1];
    int ipr[8] = {ia.x, ia.y, ia.z, ia.w, ib.x, ib.y, ib.z, ib.w};
    bf16x8 Ga[8], Gb[8];
    #pragma unroll
    for (int t = 0; t < 8; t++) {
        const unsigned short* base = rin + (size_t)ipr[t] * 64;
        Ga[t] = *(const bf16x8*)(base + q * 8);
        Gb[t] = *(const bf16x8*)(base + 32 + q * 8);
    }
    f32x4 acc[8];
    #pragma unroll
    for (int nb = 0; nb < 8; nb++) acc[nb] = (f32x4)0.f;
    bf16x8 z8 = (bf16x8)(short)0;
    #pragma unroll
    for (int t = 0; t < 8; t++) {
        bool valid = (m >> t) & 1u;
        float4 f0, f1, f2, f3;
        b2f8(Ga[t], f0, f1); b2f8(Gb[t], f2, f3);
        int c0 = q * 8;
        f0 = nrm4(f0, ss, tt, c0);      f1 = nrm4(f1, ss, tt, c0 + 4);
        f2 = nrm4(f2, ss, tt, 32 + c0); f3 = nrm4(f3, ss, tt, 32 + c0 + 4);
        if (valid) {
            float* dpp = nout + (size_t)ipr[t] * 64;
            ntst(dpp + q * 8, f0);      ntst(dpp + q * 8 + 4, f1);
            ntst(dpp + 32 + q * 8, f2); ntst(dpp + 32 + q * 8 + 4, f3);
        }
        bf16x8 a0 = valid ? cvt8(f0, f1) : z8;
        bf16x8 a1 = valid ? cvt8(f2, f3) : z8;
        #pragma unroll
        for (int nb = 0; nb < 8; nb++) {
            bf16x8 b0 = *(const bf16x8*)(Wsh + ((size_t)(t * 16 + nb) * 64 + lane) * 8);
            acc[nb] = __builtin_amdgcn_mfma_f32_16x16x32_bf16(a0, b0, acc[nb], 0, 0, 0);
            bf16x8 b1 = *(const bf16x8*)(Wsh + ((size_t)(t * 16 + 8 + nb) * 64 + lane) * 8);
            acc[nb] = __builtin_amdgcn_mfma_f32_16x16x32_bf16(a1, b1, acc[nb], 0, 0, 0);
        }
    }
    int rowD = tile * 16 + q * 4;
    float sum[8], sq[8];
    #pragma unroll
    for (int nb = 0; nb < 8; nb++) {
        sum[nb] = 0.f; sq[nb] = 0.f;
        #pragma unroll
        for (int r = 0; r < 4; r++) {
            float v = acc[nb][r];
            rawout[(size_t)(rowD + r) * 128 + nb * 16 + li] = f2b(v);
            sum[nb] += v; sq[nb] = fmaf(v, v, sq[nb]);
        }
    }
    #pragma unroll
    for (int nb = 0; nb < 8; nb++) {
        int c = nb * 16 + li;
        atomicAdd(&ls[c], sum[nb]); atomicAdd(&ls[128 + c], sq[nb]);
    }
    __syncthreads();
    int slot = (blockIdx.x & (SLOTS - 1)) << 8;
    if (threadIdx.x < 128) {
        atomicAdd(&st[slot + threadIdx.x], ls[threadIdx.x]);
        atomicAdd(&st[slot + 128 + threadIdx.x], ls[128 + threadIdx.x]);
    }
}

// conv3: R2 bf16 -> (normalized x_up2 f32 dedup to sC) + R3 raw bf16.
// 1 row-tile per wave (lower VGPR, higher occupancy). XCD-swizzled.
__global__ __launch_bounds__(256, 4)
void k_conv3b(const unsigned short* __restrict__ rin, const unsigned short* __restrict__ Wsh,
              const int* __restrict__ par, const int* __restrict__ off,
              unsigned short* __restrict__ rawout, float* __restrict__ st, int M,
              const float* __restrict__ st_in, const float* __restrict__ gw,
              const float* __restrict__ bw, int Min, float* __restrict__ nout,
              const int* __restrict__ wmax) {
    __shared__ float ls[2 * 64];
    __shared__ float ss[128], tt[128];
    if (threadIdx.x < 128) ls[threadIdx.x] = 0.f;
    mk_norm<128>(st_in, Min, gw, bw, ss, tt);
    __syncthreads();
    const int lane = threadIdx.x & 63, wid = threadIdx.x >> 6;
    const int q = lane >> 4, li = lane & 15;
    int gi = xswz(blockIdx.x, gridDim.x);
    int tile = gi * 4 + wid;
    float sum[4] = {0, 0, 0, 0}, sq[4] = {0, 0, 0, 0};
    if (tile * 16 < M) {
        int r0 = tile * 16 + li;
        int p0 = par[r0];
        int o0 = off[r0];
        bool w0 = (wmax[p0] == r0 + 1);
        bf16x8 Xa[4];
        #pragma unroll
        for (int kb = 0; kb < 4; kb++)
            Xa[kb] = *(const bf16x8*)(rin + (size_t)p0 * 128 + kb * 32 + q * 8);
        bf16x8 A0[4];
        #pragma unroll
        for (int kb = 0; kb < 4; kb++) {
            float4 x0, x1;
            b2f8(Xa[kb], x0, x1);
            int c0 = kb * 32 + q * 8;
            x0 = nrm4(x0, ss, tt, c0); x1 = nrm4(x1, ss, tt, c0 + 4);
            if (w0) {
                float* dp = nout + (size_t)p0 * 128 + kb * 32 + q * 8;
                ntst(dp, x0); ntst(dp + 4, x1);
            }
            A0[kb] = cvt8(x0, x1);
        }
        f32x4 acc0[4];
        #pragma unroll
        for (int nb = 0; nb < 4; nb++) acc0[nb] = (f32x4)0.f;
        bf16x8 z8 = (bf16x8)(short)0;
        for (int o = 0; o < 8; o++) {
            bool s0 = (o0 == o);
            if (__ballot(s0) == 0ull) continue;
            bf16x8 M0[4];
            #pragma unroll
            for (int kb = 0; kb < 4; kb++) M0[kb] = s0 ? A0[kb] : z8;
            #pragma unroll
            for (int nb = 0; nb < 4; nb++)
                #pragma unroll
                for (int kb = 0; kb < 4; kb++) {
                    bf16x8 bb = *(const bf16x8*)(Wsh + ((((size_t)o * 4 + kb) * 4 + nb) * 64 + lane) * 8);
                    acc0[nb] = __builtin_amdgcn_mfma_f32_16x16x32_bf16(M0[kb], bb, acc0[nb], 0, 0, 0);
                }
        }
        int d0 = tile * 16 + q * 4;
        #pragma unroll
        for (int nb = 0; nb < 4; nb++)
            #pragma unroll
            for (int r = 0; r < 4; r++) {
                float v0 = acc0[nb][r];
                rawout[(size_t)(d0 + r) * 64 + nb * 16 + li] = f2b(v0);
                sum[nb] += v0;
                sq[nb] = fmaf(v0, v0, sq[nb]);
            }
    }
    #pragma unroll
    for (int nb = 0; nb < 4; nb++) {
        int c = nb * 16 + li;
        atomicAdd(&ls[c], sum[nb]); atomicAdd(&ls[64 + c], sq[nb]);
    }
    __syncthreads();
    int slot = (blockIdx.x & (SLOTS - 1)) << 8;
    if (threadIdx.x < 64) {
        atomicAdd(&st[slot + threadIdx.x], ls[threadIdx.x]);
        atomicAdd(&st[slot + 128 + threadIdx.x], ls[64 + threadIdx.x]);
    }
}

// conv4: R3 bf16 -> (normalized x_down1 f32 dedup to sB) + raw x_down2 f32 sA.
// 1 row-tile per wave. XCD-swizzled.
__global__ __launch_bounds__(256, 4)
void k_conv4b(const unsigned short* __restrict__ rin, const unsigned short* __restrict__ Wsh,
              const int* __restrict__ par, const int* __restrict__ off,
              float* __restrict__ out, float* __restrict__ st, int M,
              const float* __restrict__ st_in, const float* __restrict__ gw,
              const float* __restrict__ bw, int Min, float* __restrict__ nout,
              const int* __restrict__ wmax) {
    __shared__ unsigned short Wl[8 * 2 * 2 * 64 * 8];   // 32KB
    __shared__ float ls[2 * 32];
    __shared__ float ss[64], tt[64];
    {
        const int4* s = (const int4*)Wsh; int4* d = (int4*)Wl;
        for (int i = threadIdx.x; i < 2048; i += 256) d[i] = s[i];
    }
    if (threadIdx.x < 64) ls[threadIdx.x & 63] = 0.f;
    mk_norm<64>(st_in, Min, gw, bw, ss, tt);
    __syncthreads();
    const int lane = threadIdx.x & 63, wid = threadIdx.x >> 6;
    const int q = lane >> 4, li = lane & 15;
    int gi = xswz(blockIdx.x, gridDim.x);
    int tile = gi * 4 + wid;
    float sum[2] = {0, 0}, sq[2] = {0, 0};
    if (tile * 16 < M) {
        int r0 = tile * 16 + li;
        int p0 = par[r0];
        int o0 = off[r0];
        bool w0 = (wmax[p0] == r0 + 1);
        bf16x8 Xa[2];
        #pragma unroll
        for (int kb = 0; kb < 2; kb++)
            Xa[kb] = *(const bf16x8*)(rin + (size_t)p0 * 64 + kb * 32 + q * 8);
        bf16x8 A0[2];
        #pragma unroll
        for (int kb = 0; kb < 2; kb++) {
            float4 x0, x1;
            b2f8(Xa[kb], x0, x1);
            int c0 = kb * 32 + q * 8;
            x0 = nrm4(x0, ss, tt, c0); x1 = nrm4(x1, ss, tt, c0 + 4);
            if (w0) {
                float* dp = nout + (size_t)p0 * 64 + kb * 32 + q * 8;
                ntst(dp, x0); ntst(dp + 4, x1);
            }
            A0[kb] = cvt8(x0, x1);
        }
        f32x4 acc0[2];
        #pragma unroll
        for (int nb = 0; nb < 2; nb++) acc0[nb] = (f32x4)0.f;
        bf16x8 z8 = (bf16x8)(short)0;
        for (int o = 0; o < 8; o++) {
            bool s0 = (o0 == o);
            if (__ballot(s0) == 0ull) continue;
            bf16x8 M0[2];
            #pragma unroll
            for (int kb = 0; kb < 2; kb++) M0[kb] = s0 ? A0[kb] : z8;
            #pragma unroll
            for (int nb = 0; nb < 2; nb++)
                #pragma unroll
                for (int kb = 0; kb < 2; kb++) {
                    bf16x8 bb = *(const bf16x8*)&Wl[(((o * 2 + kb) * 2 + nb) * 64 + lane) * 8];
                    acc0[nb] = __builtin_amdgcn_mfma_f32_16x16x32_bf16(M0[kb], bb, acc0[nb], 0, 0, 0);
                }
        }
        int d0 = tile * 16 + q * 4;
        #pragma unroll
        for (int nb = 0; nb < 2; nb++)
            #pragma unroll
            for (int r = 0; r < 4; r++) {
                float v0 = acc0[nb][r];
                out[(size_t)(d0 + r) * 32 + nb * 16 + li] = v0;
                sum[nb] += v0;
                sq[nb] = fmaf(v0, v0, sq[nb]);
            }
    }
    #pragma unroll
    for (int nb = 0; nb < 2; nb++) {
        int c = nb * 16 + li;
        atomicAdd(&ls[c], sum[nb]); atomicAdd(&ls[32 + c], sq[nb]);
    }
    __syncthreads();
    int slot = (blockIdx.x & (SLOTS - 1)) << 8;
    if (threadIdx.x < 32) {
        atomicAdd(&st[slot + threadIdx.x], ls[threadIdx.x]);
        atomicAdd(&st[slot + 128 + threadIdx.x], ls[32 + threadIdx.x]);
    }
}

// ================= legacy f32 path (fallback) ===============================
__global__ __launch_bounds__(256)
void k_conv1(const float* __restrict__ xin, const unsigned short* __restrict__ Wsh,
             const int* __restrict__ idx, const unsigned char* __restrict__ pm,
             float* __restrict__ out, float* __restrict__ st, int M) {
    __shared__ unsigned short Wl[8 * 4 * 64 * 8];
    __shared__ float ls[2 * 64];
    {
        const int4* s = (const int4*)Wsh; int4* d = (int4*)Wl;
        for (int i = threadIdx.x; i < 2048; i += 256) d[i] = s[i];
    }
    if (threadIdx.x < 128) ls[threadIdx.x] = 0.f;
    __syncthreads();
    const int lane = threadIdx.x & 63, wid = threadIdx.x >> 6;
    const int q = lane >> 4, li = lane & 15;
    int tile = blockIdx.x * 4 + wid;
    float sum[4] = {0, 0, 0, 0}, sq[4] = {0, 0, 0, 0};
    if (tile * 16 < M) {
        int rowA = tile * 16 + li;
        unsigned m = pm[rowA];
        const int4* ipv = (const int4*)(idx + (size_t)rowA * 8);
        int4 ia = ipv[0], ib = ipv[1];
        int ipr[8] = {ia.x, ia.y, ia.z, ia.w, ib.x, ib.y, ib.z, ib.w};
        float4 F0[8], F1[8];
        #pragma unroll
        for (int t = 0; t < 8; t++) {
            const float4* p = (const float4*)(xin + (size_t)ipr[t] * 32 + q * 8);
            F0[t] = p[0]; F1[t] = p[1];
        }
        f32x4 acc[4];
        #pragma unroll
        for (int nb = 0; nb < 4; nb++) acc[nb] = (f32x4)0.f;
        bf16x8 z8 = (bf16x8)(short)0;
        #pragma unroll
        for (int t = 0; t < 8; t++) {
            bool valid = (m >> t) & 1u;
            bf16x8 av = valid ? cvt8(F0[t], F1[t]) : z8;
            #pragma unroll
            for (int nb = 0; nb < 4; nb++) {
                bf16x8 bb = *(const bf16x8*)&Wl[((t * 4 + nb) * 64 + lane) * 8];
                acc[nb] = __builtin_amdgcn_mfma_f32_16x16x32_bf16(av, bb, acc[nb], 0, 0, 0);
            }
        }
        int rowD = tile * 16 + q * 4;
        #pragma unroll
        for (int nb = 0; nb < 4; nb++)
            #pragma unroll
            for (int r = 0; r < 4; r++) {
                float v = acc[nb][r];
                out[(size_t)(rowD + r) * 64 + nb * 16 + li] = v;
                sum[nb] += v; sq[nb] = fmaf(v, v, sq[nb]);
            }
    }
    #pragma unroll
    for (int nb = 0; nb < 4; nb++) {
        int c = nb * 16 + li;
        atomicAdd(&ls[c], sum[nb]); atomicAdd(&ls[64 + c], sq[nb]);
    }
    __syncthreads();
    int slot = (blockIdx.x & (SLOTS - 1)) << 8;
    if (threadIdx.x < 64) {
        atomicAdd(&st[slot + threadIdx.x], ls[threadIdx.x]);
        atomicAdd(&st[slot + 128 + threadIdx.x], ls[64 + threadIdx.x]);
    }
}

__global__ __launch_bounds__(256)
void k_conv2(const float* __restrict__ xin, const unsigned short* __restrict__ Wsh,
             const int* __restrict__ idx, const unsigned char* __restrict__ pm,
             float* __restrict__ out, float* __restrict__ st, int M) {
    __shared__ float ls[2 * 128];
    ls[threadIdx.x] = 0.f;
    __syncthreads();
    const int lane = threadIdx.x & 63, wid = threadIdx.x >> 6;
    const int q = lane >> 4, li = lane & 15;
    int tile = blockIdx.x * 4 + wid;
    int rowA = tile * 16 + li;
    unsigned m = pm[rowA];
    const int4* ipv = (const int4*)(idx + (size_t)rowA * 8);
    int4 ia = ipv[0], ib = ipv[1];
    int ipr[8] = {ia.x, ia.y, ia.z, ia.w, ib.x, ib.y, ib.z, ib.w};
    f32x4 acc[8];
    #pragma unroll
    for (int nb = 0; nb < 8; nb++) acc[nb] = (f32x4)0.f;
    bf16x8 z8 = (bf16x8)(short)0;
    #pragma unroll
    for (int h = 0; h < 2; h++) {
        float4 G[4][4];
        #pragma unroll
        for (int t = 0; t < 4; t++) {
            const float* base = xin + (size_t)ipr[h * 4 + t] * 64;
            const float4* p0 = (const float4*)(base + q * 8);
            const float4* p1 = (const float4*)(base + 32 + q * 8);
            G[t][0] = p0[0]; G[t][1] = p0[1]; G[t][2] = p1[0]; G[t][3] = p1[1];
        }
        #pragma unroll
        for (int t = 0; t < 4; t++) {
            int tp = h * 4 + t;
            bool valid = (m >> tp) & 1u;
            bf16x8 a0 = valid ? cvt8(G[t][0], G[t][1]) : z8;
            bf16x8 a1 = valid ? cvt8(G[t][2], G[t][3]) : z8;
            #pragma unroll
            for (int nb = 0; nb < 8; nb++) {
                bf16x8 b0 = *(const bf16x8*)(Wsh + ((size_t)(tp * 16 + nb) * 64 + lane) * 8);
                acc[nb] = __builtin_amdgcn_mfma_f32_16x16x32_bf16(a0, b0, acc[nb], 0, 0, 0);
                bf16x8 b1 = *(const bf16x8*)(Wsh + ((size_t)(tp * 16 + 8 + nb) * 64 + lane) * 8);
                acc[nb] = __builtin_amdgcn_mfma_f32_16x16x32_bf16(a1, b1, acc[nb], 0, 0, 0);
            }
        }
    }
    int rowD = tile * 16 + q * 4;
    float sum[8], sq[8];
    #pragma unroll
    for (int nb = 0; nb < 8; nb++) {
        sum[nb] = 0.f; sq[nb] = 0.f;
        #pragma unroll
        for (int r = 0; r < 4; r++) {
            float v = acc[nb][r];
            out[(size_t)(rowD + r) * 128 + nb * 16 + li] = v;
            sum[nb] += v; sq[nb] = fmaf(v, v, sq[nb]);
        }
    }
    #pragma unroll
    for (int nb = 0; nb < 8; nb++) {
        int c = nb * 16 + li;
        atomicAdd(&ls[c], sum[nb]); atomicAdd(&ls[128 + c], sq[nb]);
    }
    __syncthreads();
    int slot = (blockIdx.x & (SLOTS - 1)) << 8;
    if (threadIdx.x < 128) {
        atomicAdd(&st[slot + threadIdx.x], ls[threadIdx.x]);
        atomicAdd(&st[slot + 128 + threadIdx.x], ls[128 + threadIdx.x]);
    }
}

__global__ __launch_bounds__(256)
void k_conv3(const float* __restrict__ xin, const unsigned short* __restrict__ Wsh,
             const int* __restrict__ par, const int* __restrict__ off,
             float* __restrict__ out, float* __restrict__ st, int M) {
    __shared__ float ls[2 * 64];
    if (threadIdx.x < 128) ls[threadIdx.x] = 0.f;
    __syncthreads();
    const int lane = threadIdx.x & 63, wid = threadIdx.x >> 6;
    const int q = lane >> 4, li = lane & 15;
    int pid = blockIdx.x * 4 + wid;
    float sum[4] = {0, 0, 0, 0}, sq[4] = {0, 0, 0, 0};
    if (pid * 32 < M) {
        int r0 = pid * 32 + li, r1 = r0 + 16;
        int p0 = par[r0], p1 = par[r1];
        int o0 = off[r0], o1 = off[r1];
        bf16x8 A0[4], A1[4];
        #pragma unroll
        for (int kb = 0; kb < 4; kb++) {
            const float4* pa = (const float4*)(xin + (size_t)p0 * 128 + kb * 32 + q * 8);
            A0[kb] = cvt8(pa[0], pa[1]);
            const float4* pb = (const float4*)(xin + (size_t)p1 * 128 + kb * 32 + q * 8);
            A1[kb] = cvt8(pb[0], pb[1]);
        }
        f32x4 acc0[4], acc1[4];
        #pragma unroll
        for (int nb = 0; nb < 4; nb++) { acc0[nb] = (f32x4)0.f; acc1[nb] = (f32x4)0.f; }
        bf16x8 z8 = (bf16x8)(short)0;
        for (int o = 0; o < 8; o++) {
            bool s0 = (o0 == o), s1 = (o1 == o);
            if (__ballot(s0 || s1) == 0ull) continue;
            bf16x8 M0[4], M1[4];
            #pragma unroll
            for (int kb = 0; kb < 4; kb++) {
                M0[kb] = s0 ? A0[kb] : z8;
                M1[kb] = s1 ? A1[kb] : z8;
            }
            #pragma unroll
            for (int nb = 0; nb < 4; nb++)
                #pragma unroll
                for (int kb = 0; kb < 4; kb++) {
                    bf16x8 bb = *(const bf16x8*)(Wsh + ((((size_t)o * 4 + kb) * 4 + nb) * 64 + lane) * 8);
                    acc0[nb] = __builtin_amdgcn_mfma_f32_16x16x32_bf16(M0[kb], bb, acc0[nb], 0, 0, 0);
                    acc1[nb] = __builtin_amdgcn_mfma_f32_16x16x32_bf16(M1[kb], bb, acc1[nb], 0, 0, 0);
                }
        }
        int d0 = pid * 32 + q * 4, d1 = d0 + 16;
        #pragma unroll
        for (int nb = 0; nb < 4; nb++)
            #pragma unroll
            for (int r = 0; r < 4; r++) {
                float v0 = acc0[nb][r], v1 = acc1[nb][r];
                out[(size_t)(d0 + r) * 64 + nb * 16 + li] = v0;
                out[(size_t)(d1 + r) * 64 + nb * 16 + li] = v1;
                sum[nb] += v0 + v1;
                sq[nb] = fmaf(v0, v0, sq[nb]); sq[nb] = fmaf(v1, v1, sq[nb]);
            }
    }
    #pragma unroll
    for (int nb = 0; nb < 4; nb++) {
        int c = nb * 16 + li;
        atomicAdd(&ls[c], sum[nb]); atomicAdd(&ls[64 + c], sq[nb]);
    }
    __syncthreads();
    int slot = (blockIdx.x & (SLOTS - 1)) << 8;
    if (threadIdx.x < 64) {
        atomicAdd(&st[slot + threadIdx.x], ls[threadIdx.x]);
        atomicAdd(&st[slot + 128 + threadIdx.x], ls[64 + threadIdx.x]);
    }
}

__global__ __launch_bounds__(256)
void k_conv4(const float* __restrict__ xin, const unsigned short* __restrict__ Wsh,
             const int* __restrict__ par, const int* __restrict__ off,
             float* __restrict__ out, float* __restrict__ st, int M) {
    __shared__ unsigned short Wl[8 * 2 * 2 * 64 * 8];
    __shared__ float ls[2 * 32];
    {
        const int4* s = (const int4*)Wsh; int4* d = (int4*)Wl;
        for (int i = threadIdx.x; i < 2048; i += 256) d[i] = s[i];
    }
    if (threadIdx.x < 64) ls[threadIdx.x] = 0.f;
    __syncthreads();
    const int lane = threadIdx.x & 63, wid = threadIdx.x >> 6;
    const int q = lane >> 4, li = lane & 15;
    int pid = blockIdx.x * 4 + wid;
    float sum[2] = {0, 0}, sq[2] = {0, 0};
    if (pid * 32 < M) {
        int r0 = pid * 32 + li, r1 = r0 + 16;
        int p0 = par[r0], p1 = par[r1];
        int o0 = off[r0], o1 = off[r1];
        bf16x8 A0[2], A1[2];
        #pragma unroll
        for (int kb = 0; kb < 2; kb++) {
            const float4* pa = (const float4*)(xin + (size_t)p0 * 64 + kb * 32 + q * 8);
            A0[kb] = cvt8(pa[0], pa[1]);
            const float4* pb = (const float4*)(xin + (size_t)p1 * 64 + kb * 32 + q * 8);
            A1[kb] = cvt8(pb[0], pb[1]);
        }
        f32x4 acc0[2], acc1[2];
        #pragma unroll
        for (int nb = 0; nb < 2; nb++) { acc0[nb] = (f32x4)0.f; acc1[nb] = (f32x4)0.f; }
        bf16x8 z8 = (bf16x8)(short)0;
        for (int o = 0; o < 8; o++) {
            bool s0 = (o0 == o), s1 = (o1 == o);
            if (__ballot(s0 || s1) == 0ull) continue;
            bf16x8 M0[2], M1[2];
            #pragma unroll
            for (int kb = 0; kb < 2; kb++) {
                M0[kb] = s0 ? A0[kb] : z8;
                M1[kb] = s1 ? A1[kb] : z8;
            }
            #pragma unroll
            for (int nb = 0; nb < 2; nb++)
                #pragma unroll
                for (int kb = 0; kb < 2; kb++) {
                    bf16x8 bb = *(const bf16x8*)&Wl[(((o * 2 + kb) * 2 + nb) * 64 + lane) * 8];
                    acc0[nb] = __builtin_amdgcn_mfma_f32_16x16x32_bf16(M0[kb], bb, acc0[nb], 0, 0, 0);
                    acc1[nb] = __builtin_amdgcn_mfma_f32_16x16x32_bf16(M1[kb], bb, acc1[nb], 0, 0, 0);
                }
        }
        int d0 = pid * 32 + q * 4, d1 = d0 + 16;
        #pragma unroll
        for (int nb = 0; nb < 2; nb++)
            #pragma unroll
            for (int r = 0; r < 4; r++) {
                float v0 = acc0[nb][r], v1 = acc1[nb][r];
                out[(size_t)(d0 + r) * 32 + nb * 16 + li] = v0;
                out[(size_t)(d1 + r) * 32 + nb * 16 + li] = v1;
                sum[nb] += v0 + v1;
                sq[nb] = fmaf(v0, v0, sq[nb]); sq[nb] = fmaf(v1, v1, sq[nb]);
            }
    }
    #pragma unroll
    for (int nb = 0; nb < 2; nb++) {
        int c = nb * 16 + li;
        atomicAdd(&ls[c], sum[nb]); atomicAdd(&ls[32 + c], sq[nb]);
    }
    __syncthreads();
    int slot = (blockIdx.x & (SLOTS - 1)) << 8;
    if (threadIdx.x < 32) {
        atomicAdd(&st[slot + threadIdx.x], ls[threadIdx.x]);
        atomicAdd(&st[slot + 128 + threadIdx.x], ls[32 + threadIdx.x]);
    }
}

template <int C>
__global__ __launch_bounds__(256)
void k_norm(float* __restrict__ f, int M, const float* __restrict__ st,
            const float* __restrict__ g, const float* __restrict__ b) {
    __shared__ float sc[C], sh[C];
    if (threadIdx.x < C) {
        int c = threadIdx.x;
        float s0, s1; slot_sum(st, c, s0, s1);
        float invM = 1.0f / (float)M;
        float mu = s0 * invM;
        float var = fmaf(s1, invM, -mu * mu);
        float s = rsqrtf(var + EPS_V) * g[c];
        sc[c] = s;
        sh[c] = fmaf(-mu, s, b[c]);
    }
    __syncthreads();
    const int total = M * (C / 4);
    const int cq = C / 4;
    float4* p = (float4*)f;
    for (int i = blockIdx.x * blockDim.x + threadIdx.x; i < total;
         i += gridDim.x * blockDim.x) {
        float4 v = p[i];
        int c0 = (i % cq) * 4;
        v.x = fmaf(v.x, sc[c0 + 0], sh[c0 + 0]);
        v.y = fmaf(v.y, sc[c0 + 1], sh[c0 + 1]);
        v.z = fmaf(v.z, sc[c0 + 2], sh[c0 + 2]);
        v.w = fmaf(v.w, sc[c0 + 3], sh[c0 + 3]);
        ntst((float*)(p + i), v);
    }
}

extern "C" void kernel_launch(void* const* d_in, const int* in_sizes, int n_in,
                              void* d_out, int out_size, void* d_ws, size_t ws_size,
                              hipStream_t stream) {
    const float* x   = (const float*)d_in[0];
    const float* W1  = (const float*)d_in[1];
    const float* W2  = (const float*)d_in[2];
    const float* W3  = (const float*)d_in[3];
    const float* W4  = (const float*)d_in[4];
    const float* g1  = (const float*)d_in[5];
    const float* b1  = (const float*)d_in[6];
    const float* g2  = (const float*)d_in[7];
    const float* b2  = (const float*)d_in[8];
    const float* g3  = (const float*)d_in[9];
    const float* b3  = (const float*)d_in[10];
    const float* g4  = (const float*)d_in[11];
    const float* b4  = (const float*)d_in[12];
    const int*  idx1 = (const int*)d_in[13];
    const void* msk1 = d_in[14];
    const int*  idx2 = (const int*)d_in[15];
    const void* msk2 = d_in[16];
    const int*  par2 = (const int*)d_in[17];
    const int*  off2 = (const int*)d_in[18];
    const int*  par1 = (const int*)d_in[19];
    const int*  off1 = (const int*)d_in[20];

    const int N1 = in_sizes[17];
    const int N0 = in_sizes[19];
    const int N2 = in_sizes[15] / 8;

    float* outp = (float*)d_out;
    float* sA = outp;                          // x_down2 [N0,32]
    float* sB = sA + (size_t)N0 * 32;          // x_down1 [N1,64]
    float* sC = sB + (size_t)N1 * 64;          // x_up2   [N2,128]
    float* sD = sC + (size_t)N2 * 128;         // x_up1   [N1,64]

    char* w = (char*)d_ws;
    float* st1 = (float*)(w + 256);
    float* st2 = st1 + SLOTS * 256;
    float* st3 = st2 + SLOTS * 256;
    float* st4 = st3 + SLOTS * 256;

    auto al = [](size_t v) { return (v + 255) & ~(size_t)255; };

    // layout: pad | st | wm2 | wm1 (zeroed prefix) | weights | pm | R1..R3
    size_t o = 256 + (size_t)4 * SLOTS * 256 * 4;
    size_t oWm2 = o; o += (size_t)N2 * 4;
    size_t oWm1 = o; o += (size_t)N1 * 4; o = al(o);
    size_t zEnd = o;
    size_t oS1 = o;  o += 32768;
    size_t oS2 = o;  o += 131072;
    size_t oS3 = o;  o += 131072;
    size_t oS4 = o;  o += 32768;
    size_t oP1 = o;  o += al((size_t)N1);
    size_t oP2 = o;  o += al((size_t)N2); o = al(o);
    size_t oR1 = o;  o += (size_t)N1 * 64 * 2;
    size_t oR2 = o;  o += (size_t)N2 * 128 * 2;
    size_t oR3 = o;  o += (size_t)N1 * 64 * 2;
    size_t need = o;

    const bool fused = (ws_size >= need);

    unsigned short* ws1p = (unsigned short*)(w + oS1);
    unsigned short* ws2p = (unsigned short*)(w + oS2);
    unsigned short* ws3p = (unsigned short*)(w + oS3);
    unsigned short* ws4p = (unsigned short*)(w + oS4);
    unsigned char* pm1 = (unsigned char*)(w + oP1);
    unsigned char* pm2 = (unsigned char*)(w + oP2);
    int* wm2 = (int*)(w + oWm2);
    int* wm1 = (int*)(w + oWm1);
    unsigned short* R1 = (unsigned short*)(w + oR1);
    unsigned short* R2 = (unsigned short*)(w + oR2);
    unsigned short* R3 = (unsigned short*)(w + oR3);

    hipMemsetAsync(d_ws, 0, fused ? zEnd : (256 + (size_t)4 * SLOTS * 256 * 4), stream);

    int P1b = (N1 + 255) / 256, P2b = (N2 + 255) / 256;
    int PW = fused ? (P1b + (N0 + 255) / 256) : 0;
    k_prep<<<P1b + P2b + 80 + PW, 256, 0, stream>>>(
        msk1, N1, msk2, N2, pm1, pm2,
        W1, W2, W3, W4, ws1p, ws2p, ws3p, ws4p,
        par2, wm2, par1, wm1, N0, fused ? 1 : 0);

    if (fused) {
        // L1: x -> R1 (bf16 raw)
        k_conv1b<<<(N1 / 16 + 3) / 4, 256, 0, stream>>>(x, ws1p, idx1, pm1, R1, st1, N1);
        // L2: R1 -> normalized x_up1 (sD) + R2 (bf16 raw)
        k_conv2b<<<(N2 / 16) / 4, 256, 0, stream>>>(R1, ws2p, idx2, pm2, R2, st2, N2,
                                                    st1, g1, b1, N1, sD);
        // L3: R2 -> normalized x_up2 (sC, dedup) + R3 (bf16 raw); 1-tile waves
        k_conv3b<<<(N1 / 16 + 3) / 4, 256, 0, stream>>>(R2, ws3p, par2, off2, R3, st3, N1,
                                                        st2, g2, b2, N2, sC, wm2);
        // L4: R3 -> normalized x_down1 (sB, dedup) + raw x_down2 (sA f32)
        k_conv4b<<<(N0 / 16 + 3) / 4, 256, 0, stream>>>(R3, ws4p, par1, off1, sA, st4, N0,
                                                        st3, g3, b3, N1, sB, wm1);
        k_norm<32><<<2048, 256, 0, stream>>>(sA, N0, st4, g4, b4);
    } else {
        // legacy: f32 convs into output slots + separate norms
        k_conv1<<<(N1 / 16 + 3) / 4, 256, 0, stream>>>(x, ws1p, idx1, pm1, sD, st1, N1);
        k_norm<64><<<1024, 256, 0, stream>>>(sD, N1, st1, g1, b1);
        k_conv2<<<(N2 / 16) / 4, 256, 0, stream>>>(sD, ws2p, idx2, pm2, sC, st2, N2);
        k_norm<128><<<512, 256, 0, stream>>>(sC, N2, st2, g2, b2);
        k_conv3<<<(N1 / 32 + 3) / 4, 256, 0, stream>>>(sC, ws3p, par2, off2, sB, st3, N1);
        k_norm<64><<<1024, 256, 0, stream>>>(sB, N1, st3, g3, b3);
        k_conv4<<<(N0 / 32 + 3) / 4, 256, 0, stream>>>(sB, ws4p, par1, off1, sA, st4, N0);
        k_norm<32><<<2048, 256, 0, stream>>>(sA, N0, st4, g4, b4);
    }
}

// Round 7
// 548.776 us; speedup vs baseline: 1.0923x; 1.0923x over previous
//
#include <hip/hip_runtime.h>
#include <cstdint>
#include <cstddef>

#define EPS_V 1e-5f
#define SLOTS 16

typedef __attribute__((ext_vector_type(8))) short bf16x8;
typedef __attribute__((ext_vector_type(4))) float f32x4;

__device__ __forceinline__ unsigned short f2b(float f) {
    unsigned u = __float_as_uint(f);
    u = (u + 0x7FFFu + ((u >> 16) & 1u)) >> 16;      // RNE
    return (unsigned short)u;
}

__device__ __forceinline__ bf16x8 cvt8(float4 a, float4 b) {
    bf16x8 r;
    r[0] = (short)f2b(a.x); r[1] = (short)f2b(a.y);
    r[2] = (short)f2b(a.z); r[3] = (short)f2b(a.w);
    r[4] = (short)f2b(b.x); r[5] = (short)f2b(b.y);
    r[6] = (short)f2b(b.z); r[7] = (short)f2b(b.w);
    return r;
}

__device__ __forceinline__ float4 nrm4(float4 v, const float* ss, const float* tt, int c) {
    v.x = fmaf(v.x, ss[c + 0], tt[c + 0]);
    v.y = fmaf(v.y, ss[c + 1], tt[c + 1]);
    v.z = fmaf(v.z, ss[c + 2], tt[c + 2]);
    v.w = fmaf(v.w, ss[c + 3], tt[c + 3]);
    return v;
}

// nontemporal float4 store (final outputs, never re-read on device)
__device__ __forceinline__ void ntst(float* p, float4 v) {
    f32x4 w; w[0] = v.x; w[1] = v.y; w[2] = v.z; w[3] = v.w;
    __builtin_nontemporal_store(w, (f32x4*)p);
}

__device__ __forceinline__ void slot_sum(const float* st, int c, float& s0, float& s1) {
    s0 = 0.f; s1 = 0.f;
    #pragma unroll
    for (int s = 0; s < SLOTS; s++) {
        s0 += st[s * 256 + c];
        s1 += st[s * 256 + 128 + c];
    }
}

// ---------------- fused preprocessing: detect + pack + wshuf + writer-max ---
__device__ __forceinline__ void pack_one(const void* mask, int r, int isByte,
                                         unsigned char* pm) {
    unsigned byte = 0;
    if (isByte) {
        const unsigned char* mb = (const unsigned char*)mask;
        #pragma unroll
        for (int k = 0; k < 8; k++) byte |= (mb[(size_t)r * 8 + k] ? 1u : 0u) << k;
    } else {
        const int* mi = (const int*)mask;
        #pragma unroll
        for (int k = 0; k < 8; k++) byte |= (mi[(size_t)r * 8 + k] ? 1u : 0u) << k;
    }
    pm[r] = (unsigned char)byte;
}

// Wshuf[((t*KB+kb)*NB+nb)*64 + L][j] = bf16( W[t][kb*32 + (L>>4)*8 + j][nb*16 + (L&15)] )
__device__ __forceinline__ void wshuf_one(const float* W, int Cin, int Cout,
                                          unsigned short* dst, int g) {
    int KB = Cin >> 5, NB = Cout >> 4;
    int L = g & 63;
    int rest = g >> 6;
    int nb = rest % NB; rest /= NB;
    int kb = rest % KB; int t = rest / KB;
    int q = L >> 4, col = nb * 16 + (L & 15);
    const float* src = W + ((size_t)t * Cin + kb * 32 + q * 8) * Cout + col;
    unsigned short* d = dst + (size_t)g * 8;
    #pragma unroll
    for (int j = 0; j < 8; j++) d[j] = f2b(src[(size_t)j * Cout]);
}

__global__ __launch_bounds__(256)
void k_prep(const void* msk1, int M1, const void* msk2, int M2,
            unsigned char* __restrict__ pm1, unsigned char* __restrict__ pm2,
            const float* __restrict__ W1, const float* __restrict__ W2,
            const float* __restrict__ W3, const float* __restrict__ W4,
            unsigned short* __restrict__ ws1, unsigned short* __restrict__ ws2,
            unsigned short* __restrict__ ws3, unsigned short* __restrict__ ws4,
            const int* __restrict__ par2, int* __restrict__ wmax2,
            const int* __restrict__ par1, int* __restrict__ wmax1,
            int N0, int do_wmax) {
    __shared__ int sfl;
    int P1 = (M1 + 255) >> 8, P2 = (M2 + 255) >> 8;
    int b = blockIdx.x, tid = threadIdx.x;
    if (b < P1 + P2) {
        // per-block dtype detection on a fixed msk1 window (L2-hot)
        if (tid == 0) sfl = 0;
        __syncthreads();
        const unsigned* wm = (const unsigned*)msk1;
        int nw = M1 * 2; if (nw > 4096) nw = 4096;
        unsigned loc = 0;
        for (int i = tid; i < nw; i += 256) if (wm[i] > 1u) loc = 1u;
        if (loc) atomicOr(&sfl, 1);
        __syncthreads();
        int isB = sfl;
        if (b < P1) { int r = b * 256 + tid; if (r < M1) pack_one(msk1, r, isB, pm1); }
        else { int r = (b - P1) * 256 + tid; if (r < M2) pack_one(msk2, r, isB, pm2); }
        return;
    }
    b -= P1 + P2;
    if (b < 8)  { wshuf_one(W1, 32, 64,  ws1, b * 256 + tid); return; }
    b -= 8;
    if (b < 32) { wshuf_one(W2, 64, 128, ws2, b * 256 + tid); return; }
    b -= 32;
    if (b < 32) { wshuf_one(W3, 128, 64, ws3, b * 256 + tid); return; }
    b -= 32;
    if (b < 8)  { wshuf_one(W4, 64, 32,  ws4, b * 256 + tid); return; }
    b -= 8;
    if (!do_wmax) return;
    if (b < P1) { int r = b * 256 + tid; if (r < M1) atomicMax(&wmax2[par2[r]], r + 1); return; }
    b -= P1;
    { int r = b * 256 + tid; if (r < N0) atomicMax(&wmax1[par1[r]], r + 1); }
}

// ---------------- conv1: sparse, Cin=32, Cout=64; 8-deep staged gathers -----
__global__ __launch_bounds__(256)
void k_conv1(const float* __restrict__ xin, const unsigned short* __restrict__ Wsh,
             const int* __restrict__ idx, const unsigned char* __restrict__ pm,
             float* __restrict__ out, float* __restrict__ st, int M) {
    __shared__ unsigned short Wl[8 * 4 * 64 * 8];   // 32KB
    __shared__ float ls[2 * 64];
    {
        const int4* s = (const int4*)Wsh; int4* d = (int4*)Wl;
        for (int i = threadIdx.x; i < 2048; i += 256) d[i] = s[i];
    }
    if (threadIdx.x < 128) ls[threadIdx.x] = 0.f;
    __syncthreads();
    const int lane = threadIdx.x & 63, wid = threadIdx.x >> 6;
    const int q = lane >> 4, li = lane & 15;
    int tile = blockIdx.x * 4 + wid;
    float sum[4] = {0, 0, 0, 0}, sq[4] = {0, 0, 0, 0};
    if (tile * 16 < M) {
        int rowA = tile * 16 + li;
        unsigned m = pm[rowA];
        const int4* ipv = (const int4*)(idx + (size_t)rowA * 8);
        int4 ia = ipv[0], ib = ipv[1];
        int ipr[8] = {ia.x, ia.y, ia.z, ia.w, ib.x, ib.y, ib.z, ib.w};
        // stage all 8 gathers (invalid slots have clamped idx 0 -> L1-hot)
        float4 F0[8], F1[8];
        #pragma unroll
        for (int t = 0; t < 8; t++) {
            const float4* p = (const float4*)(xin + (size_t)ipr[t] * 32 + q * 8);
            F0[t] = p[0]; F1[t] = p[1];
        }
        f32x4 acc[4];
        #pragma unroll
        for (int nb = 0; nb < 4; nb++) acc[nb] = (f32x4)0.f;
        bf16x8 z8 = (bf16x8)(short)0;
        #pragma unroll
        for (int t = 0; t < 8; t++) {
            bool valid = (m >> t) & 1u;
            bf16x8 av = valid ? cvt8(F0[t], F1[t]) : z8;
            #pragma unroll
            for (int nb = 0; nb < 4; nb++) {
                bf16x8 bb = *(const bf16x8*)&Wl[((t * 4 + nb) * 64 + lane) * 8];
                acc[nb] = __builtin_amdgcn_mfma_f32_16x16x32_bf16(av, bb, acc[nb], 0, 0, 0);
            }
        }
        int rowD = tile * 16 + q * 4;
        #pragma unroll
        for (int nb = 0; nb < 4; nb++)
            #pragma unroll
            for (int r = 0; r < 4; r++) {
                float v = acc[nb][r];
                out[(size_t)(rowD + r) * 64 + nb * 16 + li] = v;
                sum[nb] += v; sq[nb] = fmaf(v, v, sq[nb]);
            }
    }
    #pragma unroll
    for (int nb = 0; nb < 4; nb++) {
        int c = nb * 16 + li;
        atomicAdd(&ls[c], sum[nb]); atomicAdd(&ls[64 + c], sq[nb]);
    }
    __syncthreads();
    int slot = (blockIdx.x & (SLOTS - 1)) << 8;
    if (threadIdx.x < 64) {
        atomicAdd(&st[slot + threadIdx.x], ls[threadIdx.x]);
        atomicAdd(&st[slot + 128 + threadIdx.x], ls[64 + threadIdx.x]);
    }
}

// ---------------- conv2: sparse, Cin=64, Cout=128; 4+4 staged, norm-on-load -
__global__ __launch_bounds__(256)
void k_conv2(const float* xin, const unsigned short* __restrict__ Wsh,
             const int* __restrict__ idx, const unsigned char* __restrict__ pm,
             float* __restrict__ out, float* __restrict__ st, int M,
             const float* __restrict__ st_in, const float* __restrict__ gw,
             const float* __restrict__ bw, int Min, float* nout) {
    __shared__ float ls[2 * 128];
    __shared__ float ss[64], tt[64];
    ls[threadIdx.x] = 0.f;
    if (st_in != nullptr && threadIdx.x < 64) {
        int c = threadIdx.x;
        float s0, s1; slot_sum(st_in, c, s0, s1);
        float invM = 1.0f / (float)Min;
        float mu = s0 * invM;
        float var = fmaf(s1, invM, -mu * mu);
        float s = rsqrtf(var + EPS_V) * gw[c];
        ss[c] = s; tt[c] = fmaf(-mu, s, bw[c]);
    }
    __syncthreads();
    const int lane = threadIdx.x & 63, wid = threadIdx.x >> 6;
    const int q = lane >> 4, li = lane & 15;
    int tile = blockIdx.x * 4 + wid;
    int rowA = tile * 16 + li;
    unsigned m = pm[rowA];
    const int4* ipv = (const int4*)(idx + (size_t)rowA * 8);
    int4 ia = ipv[0], ib = ipv[1];
    int ipr[8] = {ia.x, ia.y, ia.z, ia.w, ib.x, ib.y, ib.z, ib.w};
    const bool dn = (st_in != nullptr);
    f32x4 acc[8];
    #pragma unroll
    for (int nb = 0; nb < 8; nb++) acc[nb] = (f32x4)0.f;
    bf16x8 z8 = (bf16x8)(short)0;
    #pragma unroll
    for (int h = 0; h < 2; h++) {
        // stage 4 taps (16 float4 loads in flight)
        float4 G[4][4];
        #pragma unroll
        for (int t = 0; t < 4; t++) {
            const float* base = xin + (size_t)ipr[h * 4 + t] * 64;
            const float4* p0 = (const float4*)(base + q * 8);
            const float4* p1 = (const float4*)(base + 32 + q * 8);
            G[t][0] = p0[0]; G[t][1] = p0[1]; G[t][2] = p1[0]; G[t][3] = p1[1];
        }
        #pragma unroll
        for (int t = 0; t < 4; t++) {
            int tp = h * 4 + t;
            bool valid = (m >> tp) & 1u;
            if (dn) {
                int c0 = q * 8;
                G[t][0] = nrm4(G[t][0], ss, tt, c0);
                G[t][1] = nrm4(G[t][1], ss, tt, c0 + 4);
                G[t][2] = nrm4(G[t][2], ss, tt, 32 + c0);
                G[t][3] = nrm4(G[t][3], ss, tt, 32 + c0 + 4);
                if (valid) {
                    float* dpp = nout + (size_t)ipr[tp] * 64;
                    ntst(dpp + q * 8, G[t][0]);      ntst(dpp + q * 8 + 4, G[t][1]);
                    ntst(dpp + 32 + q * 8, G[t][2]); ntst(dpp + 32 + q * 8 + 4, G[t][3]);
                }
            }
            bf16x8 a0 = valid ? cvt8(G[t][0], G[t][1]) : z8;
            bf16x8 a1 = valid ? cvt8(G[t][2], G[t][3]) : z8;
            #pragma unroll
            for (int nb = 0; nb < 8; nb++) {
                bf16x8 b0 = *(const bf16x8*)(Wsh + ((size_t)(tp * 16 + nb) * 64 + lane) * 8);
                acc[nb] = __builtin_amdgcn_mfma_f32_16x16x32_bf16(a0, b0, acc[nb], 0, 0, 0);
                bf16x8 b1 = *(const bf16x8*)(Wsh + ((size_t)(tp * 16 + 8 + nb) * 64 + lane) * 8);
                acc[nb] = __builtin_amdgcn_mfma_f32_16x16x32_bf16(a1, b1, acc[nb], 0, 0, 0);
            }
        }
    }
    int rowD = tile * 16 + q * 4;
    float sum[8], sq[8];
    #pragma unroll
    for (int nb = 0; nb < 8; nb++) {
        sum[nb] = 0.f; sq[nb] = 0.f;
        #pragma unroll
        for (int r = 0; r < 4; r++) {
            float v = acc[nb][r];
            out[(size_t)(rowD + r) * 128 + nb * 16 + li] = v;
            sum[nb] += v; sq[nb] = fmaf(v, v, sq[nb]);
        }
    }
    #pragma unroll
    for (int nb = 0; nb < 8; nb++) {
        int c = nb * 16 + li;
        atomicAdd(&ls[c], sum[nb]); atomicAdd(&ls[128 + c], sq[nb]);
    }
    __syncthreads();
    int slot = (blockIdx.x & (SLOTS - 1)) << 8;
    if (threadIdx.x < 128) {
        atomicAdd(&st[slot + threadIdx.x], ls[threadIdx.x]);
        atomicAdd(&st[slot + 128 + threadIdx.x], ls[128 + threadIdx.x]);
    }
}

// ---------------- conv3: tconv, Cin=128, Cout=64; 2+2 staged ----------------
__global__ __launch_bounds__(256)
void k_conv3(const float* __restrict__ xin, const unsigned short* __restrict__ Wsh,
             const int* __restrict__ par, const int* __restrict__ off,
             float* __restrict__ out, float* __restrict__ st, int M,
             const float* __restrict__ st_in, const float* __restrict__ gw,
             const float* __restrict__ bw, int Min, float* __restrict__ nout,
             const int* __restrict__ wmax) {
    __shared__ float ls[2 * 64];
    __shared__ float ss[128], tt[128];
    if (threadIdx.x < 128) {
        ls[threadIdx.x & 127] = 0.f;
        if (st_in != nullptr) {
            int c = threadIdx.x;
            float s0, s1; slot_sum(st_in, c, s0, s1);
            float invM = 1.0f / (float)Min;
            float mu = s0 * invM;
            float var = fmaf(s1, invM, -mu * mu);
            float s = rsqrtf(var + EPS_V) * gw[c];
            ss[c] = s; tt[c] = fmaf(-mu, s, bw[c]);
        }
    }
    __syncthreads();
    const int lane = threadIdx.x & 63, wid = threadIdx.x >> 6;
    const int q = lane >> 4, li = lane & 15;
    int pid = blockIdx.x * 4 + wid;
    float sum[4] = {0, 0, 0, 0}, sq[4] = {0, 0, 0, 0};
    if (pid * 32 < M) {
        int r0 = pid * 32 + li, r1 = r0 + 16;
        int p0 = par[r0], p1 = par[r1];
        int o0 = off[r0], o1 = off[r1];
        const bool dn = (st_in != nullptr);
        bool w0 = dn && (wmax[p0] == r0 + 1);
        bool w1 = dn && (wmax[p1] == r1 + 1);
        bf16x8 A0[4], A1[4];
        #pragma unroll
        for (int hh = 0; hh < 2; hh++) {
            float4 X[2][2], Y[2][2];
            #pragma unroll
            for (int k2 = 0; k2 < 2; k2++) {
                int kb = hh * 2 + k2;
                const float4* pa = (const float4*)(xin + (size_t)p0 * 128 + kb * 32 + q * 8);
                X[k2][0] = pa[0]; X[k2][1] = pa[1];
                const float4* pb = (const float4*)(xin + (size_t)p1 * 128 + kb * 32 + q * 8);
                Y[k2][0] = pb[0]; Y[k2][1] = pb[1];
            }
            #pragma unroll
            for (int k2 = 0; k2 < 2; k2++) {
                int kb = hh * 2 + k2;
                if (dn) {
                    int c0 = kb * 32 + q * 8;
                    X[k2][0] = nrm4(X[k2][0], ss, tt, c0); X[k2][1] = nrm4(X[k2][1], ss, tt, c0 + 4);
                    Y[k2][0] = nrm4(Y[k2][0], ss, tt, c0); Y[k2][1] = nrm4(Y[k2][1], ss, tt, c0 + 4);
                    if (w0) {
                        float* dp = nout + (size_t)p0 * 128 + kb * 32 + q * 8;
                        ntst(dp, X[k2][0]); ntst(dp + 4, X[k2][1]);
                    }
                    if (w1) {
                        float* dp = nout + (size_t)p1 * 128 + kb * 32 + q * 8;
                        ntst(dp, Y[k2][0]); ntst(dp + 4, Y[k2][1]);
                    }
                }
                A0[kb] = cvt8(X[k2][0], X[k2][1]);
                A1[kb] = cvt8(Y[k2][0], Y[k2][1]);
            }
        }
        f32x4 acc0[4], acc1[4];
        #pragma unroll
        for (int nb = 0; nb < 4; nb++) { acc0[nb] = (f32x4)0.f; acc1[nb] = (f32x4)0.f; }
        bf16x8 z8 = (bf16x8)(short)0;
        for (int o = 0; o < 8; o++) {
            bool s0 = (o0 == o), s1 = (o1 == o);
            if (__ballot(s0 || s1) == 0ull) continue;
            bf16x8 M0[4], M1[4];
            #pragma unroll
            for (int kb = 0; kb < 4; kb++) {
                M0[kb] = s0 ? A0[kb] : z8;
                M1[kb] = s1 ? A1[kb] : z8;
            }
            #pragma unroll
            for (int nb = 0; nb < 4; nb++)
                #pragma unroll
                for (int kb = 0; kb < 4; kb++) {
                    bf16x8 bb = *(const bf16x8*)(Wsh + ((((size_t)o * 4 + kb) * 4 + nb) * 64 + lane) * 8);
                    acc0[nb] = __builtin_amdgcn_mfma_f32_16x16x32_bf16(M0[kb], bb, acc0[nb], 0, 0, 0);
                    acc1[nb] = __builtin_amdgcn_mfma_f32_16x16x32_bf16(M1[kb], bb, acc1[nb], 0, 0, 0);
                }
        }
        int d0 = pid * 32 + q * 4, d1 = d0 + 16;
        #pragma unroll
        for (int nb = 0; nb < 4; nb++)
            #pragma unroll
            for (int r = 0; r < 4; r++) {
                float v0 = acc0[nb][r], v1 = acc1[nb][r];
                out[(size_t)(d0 + r) * 64 + nb * 16 + li] = v0;
                out[(size_t)(d1 + r) * 64 + nb * 16 + li] = v1;
                sum[nb] += v0 + v1;
                sq[nb] = fmaf(v0, v0, sq[nb]); sq[nb] = fmaf(v1, v1, sq[nb]);
            }
    }
    #pragma unroll
    for (int nb = 0; nb < 4; nb++) {
        int c = nb * 16 + li;
        atomicAdd(&ls[c], sum[nb]); atomicAdd(&ls[64 + c], sq[nb]);
    }
    __syncthreads();
    int slot = (blockIdx.x & (SLOTS - 1)) << 8;
    if (threadIdx.x < 64) {
        atomicAdd(&st[slot + threadIdx.x], ls[threadIdx.x]);
        atomicAdd(&st[slot + 128 + threadIdx.x], ls[64 + threadIdx.x]);
    }
}

// ---------------- conv4: tconv, Cin=64, Cout=32; fully staged ---------------
__global__ __launch_bounds__(256)
void k_conv4(const float* __restrict__ xin, const unsigned short* __restrict__ Wsh,
             const int* __restrict__ par, const int* __restrict__ off,
             float* __restrict__ out, float* __restrict__ st, int M,
             const float* __restrict__ st_in, const float* __restrict__ gw,
             const float* __restrict__ bw, int Min, float* __restrict__ nout,
             const int* __restrict__ wmax) {
    __shared__ unsigned short Wl[8 * 2 * 2 * 64 * 8];   // 32KB
    __shared__ float ls[2 * 32];
    __shared__ float ss[64], tt[64];
    {
        const int4* s = (const int4*)Wsh; int4* d = (int4*)Wl;
        for (int i = threadIdx.x; i < 2048; i += 256) d[i] = s[i];
    }
    if (threadIdx.x < 64) {
        ls[threadIdx.x & 63] = 0.f;
        if (st_in != nullptr) {
            int c = threadIdx.x;
            float s0, s1; slot_sum(st_in, c, s0, s1);
            float invM = 1.0f / (float)Min;
            float mu = s0 * invM;
            float var = fmaf(s1, invM, -mu * mu);
            float s = rsqrtf(var + EPS_V) * gw[c];
            ss[c] = s; tt[c] = fmaf(-mu, s, bw[c]);
        }
    }
    __syncthreads();
    const int lane = threadIdx.x & 63, wid = threadIdx.x >> 6;
    const int q = lane >> 4, li = lane & 15;
    int pid = blockIdx.x * 4 + wid;
    float sum[2] = {0, 0}, sq[2] = {0, 0};
    if (pid * 32 < M) {
        int r0 = pid * 32 + li, r1 = r0 + 16;
        int p0 = par[r0], p1 = par[r1];
        int o0 = off[r0], o1 = off[r1];
        const bool dn = (st_in != nullptr);
        bool w0 = dn && (wmax[p0] == r0 + 1);
        bool w1 = dn && (wmax[p1] == r1 + 1);
        // stage all 8 loads
        float4 X[2][2], Y[2][2];
        #pragma unroll
        for (int kb = 0; kb < 2; kb++) {
            const float4* pa = (const float4*)(xin + (size_t)p0 * 64 + kb * 32 + q * 8);
            X[kb][0] = pa[0]; X[kb][1] = pa[1];
            const float4* pb = (const float4*)(xin + (size_t)p1 * 64 + kb * 32 + q * 8);
            Y[kb][0] = pb[0]; Y[kb][1] = pb[1];
        }
        bf16x8 A0[2], A1[2];
        #pragma unroll
        for (int kb = 0; kb < 2; kb++) {
            if (dn) {
                int c0 = kb * 32 + q * 8;
                X[kb][0] = nrm4(X[kb][0], ss, tt, c0); X[kb][1] = nrm4(X[kb][1], ss, tt, c0 + 4);
                Y[kb][0] = nrm4(Y[kb][0], ss, tt, c0); Y[kb][1] = nrm4(Y[kb][1], ss, tt, c0 + 4);
                if (w0) {
                    float* dp = nout + (size_t)p0 * 64 + kb * 32 + q * 8;
                    ntst(dp, X[kb][0]); ntst(dp + 4, X[kb][1]);
                }
                if (w1) {
                    float* dp = nout + (size_t)p1 * 64 + kb * 32 + q * 8;
                    ntst(dp, Y[kb][0]); ntst(dp + 4, Y[kb][1]);
                }
            }
            A0[kb] = cvt8(X[kb][0], X[kb][1]);
            A1[kb] = cvt8(Y[kb][0], Y[kb][1]);
        }
        f32x4 acc0[2], acc1[2];
        #pragma unroll
        for (int nb = 0; nb < 2; nb++) { acc0[nb] = (f32x4)0.f; acc1[nb] = (f32x4)0.f; }
        bf16x8 z8 = (bf16x8)(short)0;
        for (int o = 0; o < 8; o++) {
            bool s0 = (o0 == o), s1 = (o1 == o);
            if (__ballot(s0 || s1) == 0ull) continue;
            bf16x8 M0[2], M1[2];
            #pragma unroll
            for (int kb = 0; kb < 2; kb++) {
                M0[kb] = s0 ? A0[kb] : z8;
                M1[kb] = s1 ? A1[kb] : z8;
            }
            #pragma unroll
            for (int nb = 0; nb < 2; nb++)
                #pragma unroll
                for (int kb = 0; kb < 2; kb++) {
                    bf16x8 bb = *(const bf16x8*)&Wl[(((o * 2 + kb) * 2 + nb) * 64 + lane) * 8];
                    acc0[nb] = __builtin_amdgcn_mfma_f32_16x16x32_bf16(M0[kb], bb, acc0[nb], 0, 0, 0);
                    acc1[nb] = __builtin_amdgcn_mfma_f32_16x16x32_bf16(M1[kb], bb, acc1[nb], 0, 0, 0);
                }
        }
        int d0 = pid * 32 + q * 4, d1 = d0 + 16;
        #pragma unroll
        for (int nb = 0; nb < 2; nb++)
            #pragma unroll
            for (int r = 0; r < 4; r++) {
                float v0 = acc0[nb][r], v1 = acc1[nb][r];
                out[(size_t)(d0 + r) * 32 + nb * 16 + li] = v0;
                out[(size_t)(d1 + r) * 32 + nb * 16 + li] = v1;
                sum[nb] += v0 + v1;
                sq[nb] = fmaf(v0, v0, sq[nb]); sq[nb] = fmaf(v1, v1, sq[nb]);
            }
    }
    #pragma unroll
    for (int nb = 0; nb < 2; nb++) {
        int c = nb * 16 + li;
        atomicAdd(&ls[c], sum[nb]); atomicAdd(&ls[32 + c], sq[nb]);
    }
    __syncthreads();
    int slot = (blockIdx.x & (SLOTS - 1)) << 8;
    if (threadIdx.x < 32) {
        atomicAdd(&st[slot + threadIdx.x], ls[threadIdx.x]);
        atomicAdd(&st[slot + 128 + threadIdx.x], ls[32 + threadIdx.x]);
    }
}

// ---------------- in-place instance norm (final layer / fallback) -----------
template <int C>
__global__ __launch_bounds__(256)
void k_norm(float* __restrict__ f, int M, const float* __restrict__ st,
            const float* __restrict__ g, const float* __restrict__ b) {
    __shared__ float sc[C], sh[C];
    if (threadIdx.x < C) {
        int c = threadIdx.x;
        float s0, s1; slot_sum(st, c, s0, s1);
        float invM = 1.0f / (float)M;
        float mu = s0 * invM;
        float var = fmaf(s1, invM, -mu * mu);
        float s = rsqrtf(var + EPS_V) * g[c];
        sc[c] = s;
        sh[c] = fmaf(-mu, s, b[c]);
    }
    __syncthreads();
    const int total = M * (C / 4);
    const int cq = C / 4;
    float4* p = (float4*)f;
    for (int i = blockIdx.x * blockDim.x + threadIdx.x; i < total;
         i += gridDim.x * blockDim.x) {
        float4 v = p[i];
        int c0 = (i % cq) * 4;
        v.x = fmaf(v.x, sc[c0 + 0], sh[c0 + 0]);
        v.y = fmaf(v.y, sc[c0 + 1], sh[c0 + 1]);
        v.z = fmaf(v.z, sc[c0 + 2], sh[c0 + 2]);
        v.w = fmaf(v.w, sc[c0 + 3], sh[c0 + 3]);
        ntst((float*)(p + i), v);
    }
}

extern "C" void kernel_launch(void* const* d_in, const int* in_sizes, int n_in,
                              void* d_out, int out_size, void* d_ws, size_t ws_size,
                              hipStream_t stream) {
    const float* x   = (const float*)d_in[0];
    const float* W1  = (const float*)d_in[1];
    const float* W2  = (const float*)d_in[2];
    const float* W3  = (const float*)d_in[3];
    const float* W4  = (const float*)d_in[4];
    const float* g1  = (const float*)d_in[5];
    const float* b1  = (const float*)d_in[6];
    const float* g2  = (const float*)d_in[7];
    const float* b2  = (const float*)d_in[8];
    const float* g3  = (const float*)d_in[9];
    const float* b3  = (const float*)d_in[10];
    const float* g4  = (const float*)d_in[11];
    const float* b4  = (const float*)d_in[12];
    const int*  idx1 = (const int*)d_in[13];
    const void* msk1 = d_in[14];
    const int*  idx2 = (const int*)d_in[15];
    const void* msk2 = d_in[16];
    const int*  par2 = (const int*)d_in[17];
    const int*  off2 = (const int*)d_in[18];
    const int*  par1 = (const int*)d_in[19];
    const int*  off1 = (const int*)d_in[20];

    const int N1 = in_sizes[17];
    const int N0 = in_sizes[19];
    const int N2 = in_sizes[15] / 8;

    float* outp = (float*)d_out;
    float* sA = outp;                          // x_down2 [N0,32]
    float* sB = sA + (size_t)N0 * 32;          // x_down1 [N1,64]
    float* sC = sB + (size_t)N1 * 64;          // x_up2   [N2,128]
    float* sD = sC + (size_t)N2 * 128;         // x_up1   [N1,64]

    char* w = (char*)d_ws;
    float* st1 = (float*)(w + 256);
    float* st2 = st1 + SLOTS * 256;
    float* st3 = st2 + SLOTS * 256;
    float* st4 = st3 + SLOTS * 256;

    auto al = [](size_t v) { return (v + 255) & ~(size_t)255; };

    // layout: pad | st | wm2 | wm1 (single zeroed prefix) | weights | pm | R2 | R3
    size_t o = 256 + (size_t)4 * SLOTS * 256 * 4;
    size_t stEnd = o;
    size_t oWm2 = o; o += (size_t)N2 * 4;
    size_t oWm1 = o; o += (size_t)N1 * 4; o = al(o);
    size_t zEnd = o;
    size_t oS1 = o;  o += 32768;
    size_t oS2 = o;  o += 131072;
    size_t oS3 = o;  o += 131072;
    size_t oS4 = o;  o += 32768;
    size_t oP1 = o;  o += al((size_t)N1);
    size_t oP2 = o;  o += al((size_t)N2); o = al(o);
    size_t oR2 = o;  o += (size_t)N2 * 128 * 4;
    size_t tierB_need = o;
    size_t oR3 = o;  o += (size_t)N1 * 64 * 4;
    size_t tierA_need = o;

    const int tier = (ws_size >= tierA_need) ? 2 : (ws_size >= tierB_need) ? 1 : 0;

    unsigned short* ws1p = (unsigned short*)(w + oS1);
    unsigned short* ws2p = (unsigned short*)(w + oS2);
    unsigned short* ws3p = (unsigned short*)(w + oS3);
    unsigned short* ws4p = (unsigned short*)(w + oS4);
    unsigned char* pm1 = (unsigned char*)(w + oP1);
    unsigned char* pm2 = (unsigned char*)(w + oP2);
    int* wm2 = (int*)(w + oWm2);
    int* wm1 = (int*)(w + oWm1);
    float* R2 = (float*)(w + oR2);
    float* R3 = (float*)(w + oR3);

    // single memset covering stats (+ wmax when fused)
    hipMemsetAsync(d_ws, 0, (tier > 0) ? zEnd : stEnd, stream);

    int P1b = (N1 + 255) / 256, P2b = (N2 + 255) / 256;
    int PW = (tier > 0) ? (P1b + (N0 + 255) / 256) : 0;
    k_prep<<<P1b + P2b + 80 + PW, 256, 0, stream>>>(
        msk1, N1, msk2, N2, pm1, pm2,
        W1, W2, W3, W4, ws1p, ws2p, ws3p, ws4p,
        par2, wm2, par1, wm1, N0, (tier > 0) ? 1 : 0);

    k_conv1<<<(N1 / 16 + 3) / 4, 256, 0, stream>>>(x, ws1p, idx1, pm1, sD, st1, N1);
    if (tier == 0) k_norm<64><<<1024, 256, 0, stream>>>(sD, N1, st1, g1, b1);

    {
        float* outv = (tier > 0) ? R2 : sC;
        k_conv2<<<(N2 / 16) / 4, 256, 0, stream>>>(
            sD, ws2p, idx2, pm2, outv, st2, N2,
            (tier > 0) ? st1 : nullptr, g1, b1, N1,
            (tier > 0) ? sD : nullptr);
        if (tier == 0) k_norm<128><<<512, 256, 0, stream>>>(sC, N2, st2, g2, b2);
    }

    {
        const float* inv = (tier > 0) ? R2 : sC;
        float* outv = (tier == 2) ? R3 : sB;
        k_conv3<<<(N1 / 32 + 3) / 4, 256, 0, stream>>>(
            inv, ws3p, par2, off2, outv, st3, N1,
            (tier > 0) ? st2 : nullptr, g2, b2, N2,
            (tier > 0) ? sC : nullptr, wm2);
        if (tier != 2) k_norm<64><<<1024, 256, 0, stream>>>(sB, N1, st3, g3, b3);
    }

    {
        const float* inv = (tier == 2) ? R3 : sB;
        k_conv4<<<(N0 / 32 + 3) / 4, 256, 0, stream>>>(
            inv, ws4p, par1, off1, sA, st4, N0,
            (tier == 2) ? st3 : nullptr, g3, b3, N1,
            (tier == 2) ? sB : nullptr, wm1);
    }
    k_norm<32><<<2048, 256, 0, stream>>>(sA, N0, st4, g4, b4);
}